// Round 9
// baseline (982.298 us; speedup 1.0000x reference)
//
#include <hip/hip_runtime.h>

#define N_NODES 100000
#define N_EDGES 1600000
#define FEAT 128
#define KB 256      // coarse buckets for edge partition (node ranges)
#define BCAP 8192   // padded capacity per bucket (mean 6250)
#define TILE 2048   // edges per fillA block
#define NPB 400     // max nodes per bucket (391) padded

typedef short bf16x8 __attribute__((ext_vector_type(8)));
typedef float f32x4 __attribute__((ext_vector_type(4)));

__device__ __forceinline__ ushort f2bf(float x) {
    union { float f; unsigned int u; } v; v.f = x;
    unsigned int u = v.u;
    return (ushort)((u + 0x7fffu + ((u >> 16) & 1u)) >> 16);  // RNE
}
__device__ __forceinline__ float bf2f(ushort h) {
    union { float f; unsigned int u; } v; v.u = ((unsigned int)h) << 16;
    return v.f;
}
__device__ __forceinline__ float lo16f(unsigned int u) {
    union { float f; unsigned int u; } v; v.u = u << 16;
    return v.f;
}
__device__ __forceinline__ float hi16f(unsigned int u) {
    union { float f; unsigned int u; } v; v.u = u & 0xffff0000u;
    return v.f;
}

#define MFMA(a, b, c) __builtin_amdgcn_mfma_f32_16x16x32_bf16((a), (b), (c), 0, 0, 0)

// Sliced activation layout: 8 slices of 16 feats.
// elem (node, f) at ((f>>4)*N_NODES + node)*16 + (f&15) [ushort].
// Slice s = contiguous 3.2 MB -> resident in one XCD's 4 MB L2 when pinned.

// ---------------- CSR build ----------------

__global__ __launch_bounds__(256) void init_gcur_kernel(int* __restrict__ gcur) {
    gcur[threadIdx.x] = 0;
}

// fillA v3: per block, LDS count -> reserve run (1 global atomic/bucket) ->
// direct scatter into padded buckets.
__global__ __launch_bounds__(256) void fillA_kernel(const int* __restrict__ src,
                                                    const int* __restrict__ dst,
                                                    int* __restrict__ gcur,
                                                    int2* __restrict__ pairs) {
    __shared__ int cnt[KB];
    __shared__ int cur[KB];
    __shared__ int rbase[KB];
    int t = threadIdx.x;
    int base = blockIdx.x * TILE;
    cnt[t] = 0;
    __syncthreads();
    int myS[8], myD[8];
#pragma unroll
    for (int j = 0; j < 8; ++j) {
        int e = base + j * 256 + t;
        int s = 0, d = -1;
        if (e < N_EDGES) {
            s = src[e]; d = dst[e];
            int b = (int)(((unsigned)d * KB) / N_NODES);
            atomicAdd(&cnt[b], 1);
        }
        myS[j] = s; myD[j] = d;
    }
    __syncthreads();
    rbase[t] = atomicAdd(&gcur[t], cnt[t]);
    cur[t] = 0;
    __syncthreads();
#pragma unroll
    for (int j = 0; j < 8; ++j) {
        if (myD[j] >= 0) {
            int b = (int)(((unsigned)myD[j] * KB) / N_NODES);
            int slot = atomicAdd(&cur[b], 1);
            pairs[(size_t)b * BCAP + rbase[b] + slot] = make_int2(myS[j], myD[j]);
        }
    }
}

__global__ __launch_bounds__(256) void bucket_base_kernel(const int* __restrict__ gcur,
                                                          int* __restrict__ bbase) {
    int t = threadIdx.x;
    __shared__ int sc[KB];
    int v = gcur[t];
    sc[t] = v;
    __syncthreads();
    for (int off = 1; off < KB; off <<= 1) {
        int x = sc[t];
        int y = (t >= off) ? sc[t - off] : 0;
        __syncthreads();
        sc[t] = x + y;
        __syncthreads();
    }
    bbase[t] = sc[t] - v;
}

// fillB v2: one block per bucket; local hist + scan in LDS -> row + col.
__global__ __launch_bounds__(512) void fillB_kernel(const int2* __restrict__ pairs,
                                                    const int* __restrict__ gcur,
                                                    const int* __restrict__ bbase,
                                                    int* __restrict__ row,
                                                    int* __restrict__ col) {
    __shared__ int ssrc[BCAP];      // 32 KB
    __shared__ ushort ld16[BCAP];   // 16 KB
    __shared__ int lcnt[NPB], lex[NPB], lcur[NPB];
    __shared__ int sc[512];
    int b = blockIdx.x;
    int t = threadIdx.x;
    int n0 = (b * N_NODES + KB - 1) / KB;
    int n1 = ((b + 1) * N_NODES + KB - 1) / KB;
    if (n1 > N_NODES) n1 = N_NODES;
    int nn = n1 - n0;
    int cnt = gcur[b];
    if (cnt > BCAP) cnt = BCAP;
    int cbase = bbase[b];
    if (t < NPB) { lcnt[t] = 0; lcur[t] = 0; }
    __syncthreads();
    const int2* bp = pairs + (size_t)b * BCAP;
    for (int i = t; i < cnt; i += 512) {
        int2 pr = bp[i];
        int ld = pr.y - n0;
        atomicAdd(&lcnt[ld], 1);
        ld16[i] = (ushort)ld;
        ssrc[i] = pr.x;
    }
    __syncthreads();
    int val = (t < nn) ? lcnt[t] : 0;
    sc[t] = val;
    __syncthreads();
    for (int off = 1; off < 512; off <<= 1) {
        int x = sc[t];
        int y = (t >= off) ? sc[t - off] : 0;
        __syncthreads();
        sc[t] = x + y;
        __syncthreads();
    }
    if (t < nn) {
        int ex = sc[t] - val;
        lex[t] = ex;
        row[n0 + t] = cbase + ex;
    }
    if (b == 0 && t == 0) row[N_NODES] = N_EDGES;
    __syncthreads();
    for (int i = t; i < cnt; i += 512) {
        int ld = ld16[i];
        int pos = cbase + lex[ld] + atomicAdd(&lcur[ld], 1);
        col[pos] = ssrc[i];
    }
}

// ---------------- converts ----------------

// x fp32 -> bf16 sliced layout
__global__ __launch_bounds__(256) void convert_x_kernel(const float* __restrict__ x,
                                                        ushort* __restrict__ xs) {
    int idx = (blockIdx.x * 256 + threadIdx.x) * 4;
    if (idx >= N_NODES * FEAT) return;
    float4 v = *(const float4*)(x + idx);
    ushort4 o;
    o.x = f2bf(v.x); o.y = f2bf(v.y); o.z = f2bf(v.z); o.w = f2bf(v.w);
    int node = idx >> 7;
    int f = idx & 127;  // 4-aligned, within one 16-feat slice
    *(ushort4*)(xs + ((size_t)(f >> 4) * N_NODES + node) * 16 + (f & 15)) = o;
}

// weights fp32 -> (hi, lo) bf16 planes, zero-padded to 128 rows (dense).
__global__ __launch_bounds__(128) void convert_w_kernel(
    const float* w0, const float* w1, const float* w2, const float* w3,
    const float* w4, const float* w5, const float* w6, const float* w7,
    ushort* __restrict__ wp) {
    int m = blockIdx.y;
    int r = blockIdx.x;
    int c = threadIdx.x;
    const float* src;
    switch (m) {
        case 0: src = w0; break; case 1: src = w1; break;
        case 2: src = w2; break; case 3: src = w3; break;
        case 4: src = w4; break; case 5: src = w5; break;
        case 6: src = w6; break; default: src = w7; break;
    }
    int rows = (m >= 6) ? 40 : 128;
    float val = (r < rows) ? src[r * FEAT + c] : 0.f;
    ushort hi = f2bf(val);
    ushort lo = f2bf(val - bf2f(hi));
    wp[(size_t)m * 32768 + r * FEAT + c] = hi;
    wp[(size_t)m * 32768 + 16384 + r * FEAT + c] = lo;
}

// ---------------- aggregation: XCD-pinned slices, 8 edges/instruction ----------------
// slice = blockIdx&7 (round-robin pins slice s to XCD s). One node per wave:
// 64 lanes = 8 edge-slots x 8 lanes (dword each = 32 B slice row).
// Per 8-edge iter: 1 col load + 1 feature dword load + ~8 VALU.
// Epilogue: shfl_xor(8,16,32) over edge slots; 8 lanes store the 32 B row.

__global__ __launch_bounds__(1024) void agg_kernel(const ushort* __restrict__ hs,
                                                   const int* __restrict__ row,
                                                   const int* __restrict__ col,
                                                   ushort* __restrict__ aggS) {
    int slice = blockIdx.x & 7;
    int v = (blockIdx.x >> 3) * 16 + (threadIdx.x >> 6);
    int lane = threadIdx.x & 63;
    int g = lane >> 3;    // edge slot 0..7
    int fl = lane & 7;    // dword index within 32 B slice row
    int beg = row[v], end = row[v + 1];
    int deg = end - beg;
    const unsigned int* base =
        (const unsigned int*)hs + (size_t)slice * N_NODES * 8 + fl;
    float a0 = 0.f, a1 = 0.f;
    int endq = beg + (deg & ~7);
    for (int i = beg; i < endq; i += 8) {
        int c = col[i + g];
        unsigned int p = base[(size_t)c * 8];
        a0 += lo16f(p); a1 += hi16f(p);
    }
    if (endq < end) {
        int e = endq + g;
        bool ok = e < end;
        int c = col[ok ? e : beg];
        unsigned int p = base[(size_t)c * 8];
        float m = ok ? 1.f : 0.f;
        a0 += m * lo16f(p); a1 += m * hi16f(p);
    }
    a0 += __shfl_xor(a0, 8);  a1 += __shfl_xor(a1, 8);
    a0 += __shfl_xor(a0, 16); a1 += __shfl_xor(a1, 16);
    a0 += __shfl_xor(a0, 32); a1 += __shfl_xor(a1, 32);
    if (g == 0) {
        float invd = 1.0f / (float)(deg > 0 ? deg : 1);
        unsigned int o = (unsigned)f2bf(a0 * invd) | ((unsigned)f2bf(a1 * invd) << 16);
        ((unsigned int*)aggS)[((size_t)slice * N_NODES + v) * 8 + fl] = o;
    }
}

// ---------------- combine (layers 1-3): LDS-free bf16 MFMA, sliced A ----------------

__device__ __forceinline__ const bf16x8* sliceA(const ushort* p, int node, int k) {
    return (const bf16x8*)(p + ((size_t)(k >> 4) * N_NODES + node) * 16 + (k & 15));
}

__global__ __launch_bounds__(256) void combine_kernel(
    const ushort* __restrict__ hb, const ushort* __restrict__ aggB,
    const ushort* __restrict__ wp,   // [sHi|sLo|nHi|nLo] planes, dense
    const float* __restrict__ bias,
    ushort* __restrict__ outB, int doRelu) {
    int tid = threadIdx.x;
    int lane = tid & 63;
    int w = tid >> 6;
    int v0 = blockIdx.x * 64;
    int frow = lane & 15;
    int fk = (lane >> 4) * 8;
    int nb = w * 32;

    const ushort* sHi = wp;
    const ushort* sLo = wp + 16384;
    const ushort* nHi = wp + 32768;
    const ushort* nLo = wp + 49152;

    int mnode[4];
#pragma unroll
    for (int mt = 0; mt < 4; ++mt) {
        int v = v0 + mt * 16 + frow;
        mnode[mt] = v < N_NODES ? v : N_NODES - 1;
    }
    int n0 = nb + frow;
    int n1 = nb + 16 + frow;

    f32x4 acc[4][2];
#pragma unroll
    for (int mt = 0; mt < 4; ++mt)
#pragma unroll
        for (int nt = 0; nt < 2; ++nt) acc[mt][nt] = (f32x4)(0.f);

#pragma unroll
    for (int kt = 0; kt < 4; ++kt) {
        int k = kt * 32 + fk;
        bf16x8 Bs[2][2], Bn[2][2];
        Bs[0][0] = *(const bf16x8*)(sHi + n0 * FEAT + k);
        Bs[0][1] = *(const bf16x8*)(sLo + n0 * FEAT + k);
        Bn[0][0] = *(const bf16x8*)(nHi + n0 * FEAT + k);
        Bn[0][1] = *(const bf16x8*)(nLo + n0 * FEAT + k);
        Bs[1][0] = *(const bf16x8*)(sHi + n1 * FEAT + k);
        Bs[1][1] = *(const bf16x8*)(sLo + n1 * FEAT + k);
        Bn[1][0] = *(const bf16x8*)(nHi + n1 * FEAT + k);
        Bn[1][1] = *(const bf16x8*)(nLo + n1 * FEAT + k);
#pragma unroll
        for (int mt = 0; mt < 4; ++mt) {
            bf16x8 Ah = *sliceA(hb, mnode[mt], k);
            bf16x8 Aa = *sliceA(aggB, mnode[mt], k);
#pragma unroll
            for (int nt = 0; nt < 2; ++nt) {
                f32x4 c = acc[mt][nt];
                c = MFMA(Ah, Bs[nt][0], c);
                c = MFMA(Ah, Bs[nt][1], c);
                c = MFMA(Aa, Bn[nt][0], c);
                c = MFMA(Aa, Bn[nt][1], c);
                acc[mt][nt] = c;
            }
        }
    }

#pragma unroll
    for (int nt = 0; nt < 2; ++nt) {
        int colo = nb + nt * 16 + (lane & 15);
        float b = bias[colo];
        size_t sbase = ((size_t)(colo >> 4) * N_NODES) * 16 + (colo & 15);
#pragma unroll
        for (int mt = 0; mt < 4; ++mt) {
#pragma unroll
            for (int i = 0; i < 4; ++i) {
                int v = v0 + mt * 16 + (lane >> 4) * 4 + i;
                if (v >= N_NODES) continue;
                float r = acc[mt][nt][i] + b;
                if (doRelu) r = fmaxf(r, 0.f);
                outB[sbase + (size_t)v * 16] = f2bf(r);
            }
        }
    }
}

// ---------------- layer 4: project-then-aggregate ----------------

__global__ __launch_bounds__(256) void proj_kernel(
    const ushort* __restrict__ hb, const ushort* __restrict__ wn,
    ushort* __restrict__ pbuf) {
    int tid = threadIdx.x;
    int lane = tid & 63;
    int w = tid >> 6;
    int v0 = blockIdx.x * 128 + (w >> 1) * 64;
    int nb = (w & 1) * 32;
    int frow = lane & 15;
    int fk = (lane >> 4) * 8;
    const ushort* nHi = wn;
    const ushort* nLo = wn + 16384;

    int mnode[4];
#pragma unroll
    for (int mt = 0; mt < 4; ++mt) {
        int v = v0 + mt * 16 + frow;
        mnode[mt] = v < N_NODES ? v : N_NODES - 1;
    }
    int n0 = nb + frow;
    int n1 = nb + 16 + frow;

    f32x4 acc[4][2];
#pragma unroll
    for (int mt = 0; mt < 4; ++mt)
#pragma unroll
        for (int nt = 0; nt < 2; ++nt) acc[mt][nt] = (f32x4)(0.f);

#pragma unroll
    for (int kt = 0; kt < 4; ++kt) {
        int k = kt * 32 + fk;
        bf16x8 B0h = *(const bf16x8*)(nHi + n0 * FEAT + k);
        bf16x8 B0l = *(const bf16x8*)(nLo + n0 * FEAT + k);
        bf16x8 B1h = *(const bf16x8*)(nHi + n1 * FEAT + k);
        bf16x8 B1l = *(const bf16x8*)(nLo + n1 * FEAT + k);
#pragma unroll
        for (int mt = 0; mt < 4; ++mt) {
            bf16x8 Ah = *sliceA(hb, mnode[mt], k);
            f32x4 c0 = acc[mt][0];
            c0 = MFMA(Ah, B0h, c0);
            c0 = MFMA(Ah, B0l, c0);
            acc[mt][0] = c0;
            f32x4 c1 = acc[mt][1];
            c1 = MFMA(Ah, B1h, c1);
            c1 = MFMA(Ah, B1l, c1);
            acc[mt][1] = c1;
        }
    }

#pragma unroll
    for (int nt = 0; nt < 2; ++nt) {
        int colo = nb + nt * 16 + (lane & 15);
        if (colo >= 40) continue;
#pragma unroll
        for (int mt = 0; mt < 4; ++mt) {
#pragma unroll
            for (int i = 0; i < 4; ++i) {
                int v = v0 + mt * 16 + (lane >> 4) * 4 + i;
                if (v >= N_NODES) continue;
                pbuf[(size_t)v * 40 + colo] = f2bf(acc[mt][nt][i]);
            }
        }
    }
}

__global__ __launch_bounds__(256) void agg4_kernel(const ushort* __restrict__ pbuf,
                                                   const int* __restrict__ row,
                                                   const int* __restrict__ col,
                                                   float* __restrict__ aggP) {
    int t = blockIdx.x * 256 + threadIdx.x;
    int v = t >> 5;
    int l = t & 31;
    if (v >= N_NODES || l >= 20) return;
    int beg = row[v], end = row[v + 1];
    const unsigned int* base = (const unsigned int*)pbuf;
    float s0 = 0.f, s1 = 0.f;
    int i = beg;
    for (; i + 4 <= end; i += 4) {
        int c0 = col[i], c1 = col[i + 1], c2 = col[i + 2], c3 = col[i + 3];
        unsigned int p0 = base[(size_t)c0 * 20 + l];
        unsigned int p1 = base[(size_t)c1 * 20 + l];
        unsigned int p2 = base[(size_t)c2 * 20 + l];
        unsigned int p3 = base[(size_t)c3 * 20 + l];
        s0 += lo16f(p0); s1 += hi16f(p0);
        s0 += lo16f(p1); s1 += hi16f(p1);
        s0 += lo16f(p2); s1 += hi16f(p2);
        s0 += lo16f(p3); s1 += hi16f(p3);
    }
    for (; i < end; ++i) {
        unsigned int p = base[(size_t)col[i] * 20 + l];
        s0 += lo16f(p); s1 += hi16f(p);
    }
    int deg = end - beg;
    float invd = 1.0f / (float)(deg > 0 ? deg : 1);
    float2 o; o.x = s0 * invd; o.y = s1 * invd;
    *(float2*)(aggP + (size_t)v * 40 + 2 * l) = o;
}

__global__ __launch_bounds__(128) void combine4_kernel(
    const ushort* __restrict__ hb, const ushort* __restrict__ ws,
    const float* __restrict__ aggP, const float* __restrict__ bias,
    float* __restrict__ out) {
    int tid = threadIdx.x;
    int lane = tid & 63;
    int w = tid >> 6;
    int v0 = blockIdx.x * 64;
    int nb = w * 32;
    int frow = lane & 15;
    int fk = (lane >> 4) * 8;
    const ushort* sHi = ws;
    const ushort* sLo = ws + 16384;

    int mnode[4];
#pragma unroll
    for (int mt = 0; mt < 4; ++mt) {
        int v = v0 + mt * 16 + frow;
        mnode[mt] = v < N_NODES ? v : N_NODES - 1;
    }
    int n0 = nb + frow;
    int n1 = nb + 16 + frow;

    f32x4 acc[4][2];
#pragma unroll
    for (int mt = 0; mt < 4; ++mt)
#pragma unroll
        for (int nt = 0; nt < 2; ++nt) acc[mt][nt] = (f32x4)(0.f);

#pragma unroll
    for (int kt = 0; kt < 4; ++kt) {
        int k = kt * 32 + fk;
        bf16x8 B0h = *(const bf16x8*)(sHi + n0 * FEAT + k);
        bf16x8 B0l = *(const bf16x8*)(sLo + n0 * FEAT + k);
        bf16x8 B1h = *(const bf16x8*)(sHi + n1 * FEAT + k);
        bf16x8 B1l = *(const bf16x8*)(sLo + n1 * FEAT + k);
#pragma unroll
        for (int mt = 0; mt < 4; ++mt) {
            bf16x8 Ah = *sliceA(hb, mnode[mt], k);
            f32x4 c0 = acc[mt][0];
            c0 = MFMA(Ah, B0h, c0);
            c0 = MFMA(Ah, B0l, c0);
            acc[mt][0] = c0;
            f32x4 c1 = acc[mt][1];
            c1 = MFMA(Ah, B1h, c1);
            c1 = MFMA(Ah, B1l, c1);
            acc[mt][1] = c1;
        }
    }

#pragma unroll
    for (int nt = 0; nt < 2; ++nt) {
        int colo = nb + nt * 16 + (lane & 15);
        if (colo >= 40) continue;
        float b = bias[colo];
#pragma unroll
        for (int mt = 0; mt < 4; ++mt) {
#pragma unroll
            for (int i = 0; i < 4; ++i) {
                int v = v0 + mt * 16 + (lane >> 4) * 4 + i;
                if (v >= N_NODES) continue;
                out[(size_t)v * 40 + colo] = acc[mt][nt][i] + b + aggP[(size_t)v * 40 + colo];
            }
        }
    }
}

// ---------------- launch ----------------

static inline size_t align256(size_t x) { return (x + 255) & ~(size_t)255; }

extern "C" void kernel_launch(void* const* d_in, const int* in_sizes, int n_in,
                              void* d_out, int out_size, void* d_ws, size_t ws_size,
                              hipStream_t stream) {
    const float* x = (const float*)d_in[0];
    const int* src = (const int*)d_in[1];
    const int* dst = (const int*)d_in[2];
    const float* ws1 = (const float*)d_in[3];
    const float* wn1 = (const float*)d_in[4];
    const float* b1 = (const float*)d_in[5];
    const float* ws2 = (const float*)d_in[6];
    const float* wn2 = (const float*)d_in[7];
    const float* b2 = (const float*)d_in[8];
    const float* ws3 = (const float*)d_in[9];
    const float* wn3 = (const float*)d_in[10];
    const float* b3 = (const float*)d_in[11];
    const float* ws4 = (const float*)d_in[12];
    const float* wn4 = (const float*)d_in[13];
    const float* b4 = (const float*)d_in[14];
    float* out = (float*)d_out;

    char* base = (char*)d_ws;
    size_t off = 0;
    auto alloc = [&](size_t bytes) -> void* {
        void* p = base + off;
        off = align256(off + bytes);
        return p;
    };
    int* row = (int*)alloc((size_t)(N_NODES + 1) * 4);
    int* gcur = (int*)alloc((size_t)KB * 4);
    int* bbase = (int*)alloc((size_t)KB * 4);
    int* col = (int*)alloc((size_t)N_EDGES * 4);
    int2* pairs = (int2*)alloc((size_t)KB * BCAP * 8);   // 16.8 MB padded buckets
    ushort* wp = (ushort*)alloc((size_t)8 * 32768 * 2);
    ushort* xb = (ushort*)alloc((size_t)N_NODES * FEAT * 2);
    ushort* bufA = (ushort*)alloc((size_t)N_NODES * FEAT * 2);
    ushort* bufB = (ushort*)alloc((size_t)N_NODES * FEAT * 2);
    ushort* aggB = (ushort*)alloc((size_t)N_NODES * FEAT * 2);
    ushort* pbuf = (ushort*)alloc((size_t)N_NODES * 40 * 2);
    float* aggP = (float*)alloc((size_t)N_NODES * 40 * 4);
    (void)ws_size;

    // converts + CSR build
    convert_x_kernel<<<(N_NODES * FEAT / 4 + 255) / 256, 256, 0, stream>>>(x, xb);
    convert_w_kernel<<<dim3(128, 8), 128, 0, stream>>>(ws1, wn1, ws2, wn2, ws3, wn3,
                                                       ws4, wn4, wp);
    init_gcur_kernel<<<1, KB, 0, stream>>>(gcur);
    fillA_kernel<<<(N_EDGES + TILE - 1) / TILE, 256, 0, stream>>>(src, dst, gcur, pairs);
    bucket_base_kernel<<<1, KB, 0, stream>>>(gcur, bbase);
    fillB_kernel<<<KB, 512, 0, stream>>>(pairs, gcur, bbase, row, col);

    int cgrid = (N_NODES + 63) / 64;            // 1563
    int aggGrid = 8 * (N_NODES / 16);           // 50000 (slice = bid & 7)

    const ushort* wp1 = wp;
    const ushort* wp2 = wp + (size_t)2 * 32768;
    const ushort* wp3 = wp + (size_t)4 * 32768;
    const ushort* wp4 = wp + (size_t)6 * 32768;

    agg_kernel<<<aggGrid, 1024, 0, stream>>>(xb, row, col, aggB);
    combine_kernel<<<cgrid, 256, 0, stream>>>(xb, aggB, wp1, b1, bufA, 1);
    agg_kernel<<<aggGrid, 1024, 0, stream>>>(bufA, row, col, aggB);
    combine_kernel<<<cgrid, 256, 0, stream>>>(bufA, aggB, wp2, b2, bufB, 1);
    agg_kernel<<<aggGrid, 1024, 0, stream>>>(bufB, row, col, aggB);
    combine_kernel<<<cgrid, 256, 0, stream>>>(bufB, aggB, wp3, b3, bufA, 1);
    // layer 4: project -> aggregate(40-dim) -> self-combine
    proj_kernel<<<(N_NODES + 127) / 128, 256, 0, stream>>>(bufA, wp4 + 32768, pbuf);
    agg4_kernel<<<((size_t)N_NODES * 32 + 255) / 256, 256, 0, stream>>>(pbuf, row, col, aggP);
    combine4_kernel<<<cgrid, 128, 0, stream>>>(bufA, wp4, aggP, b4, out);
}

// Round 10
// 718.592 us; speedup vs baseline: 1.3670x; 1.3670x over previous
//
#include <hip/hip_runtime.h>

#define N_NODES 100000
#define N_EDGES 1600000
#define FEAT 128
#define KB 256      // coarse buckets for edge partition (node ranges)
#define BCAP 8192   // padded capacity per bucket (mean 6250)
#define TILE 2048   // edges per fillA block
#define NPB 400     // max nodes per bucket (391) padded

typedef short bf16x8 __attribute__((ext_vector_type(8)));
typedef float f32x4 __attribute__((ext_vector_type(4)));

__device__ __forceinline__ ushort f2bf(float x) {
    union { float f; unsigned int u; } v; v.f = x;
    unsigned int u = v.u;
    return (ushort)((u + 0x7fffu + ((u >> 16) & 1u)) >> 16);  // RNE
}
__device__ __forceinline__ float bf2f(ushort h) {
    union { float f; unsigned int u; } v; v.u = ((unsigned int)h) << 16;
    return v.f;
}
__device__ __forceinline__ float lo16f(unsigned int u) {
    union { float f; unsigned int u; } v; v.u = u << 16;
    return v.f;
}
__device__ __forceinline__ float hi16f(unsigned int u) {
    union { float f; unsigned int u; } v; v.u = u & 0xffff0000u;
    return v.f;
}

#define MFMA(a, b, c) __builtin_amdgcn_mfma_f32_16x16x32_bf16((a), (b), (c), 0, 0, 0)

// ---------------- CSR build ----------------

__global__ __launch_bounds__(256) void init_gcur_kernel(int* __restrict__ gcur) {
    gcur[threadIdx.x] = 0;
}

// fillA: per block, LDS count -> reserve run (1 global atomic/bucket) ->
// direct scatter into padded buckets.
__global__ __launch_bounds__(256) void fillA_kernel(const int* __restrict__ src,
                                                    const int* __restrict__ dst,
                                                    int* __restrict__ gcur,
                                                    int2* __restrict__ pairs) {
    __shared__ int cnt[KB];
    __shared__ int cur[KB];
    __shared__ int rbase[KB];
    int t = threadIdx.x;
    int base = blockIdx.x * TILE;
    cnt[t] = 0;
    __syncthreads();
    int myS[8], myD[8];
#pragma unroll
    for (int j = 0; j < 8; ++j) {
        int e = base + j * 256 + t;
        int s = 0, d = -1;
        if (e < N_EDGES) {
            s = src[e]; d = dst[e];
            int b = (int)(((unsigned)d * KB) / N_NODES);
            atomicAdd(&cnt[b], 1);
        }
        myS[j] = s; myD[j] = d;
    }
    __syncthreads();
    rbase[t] = atomicAdd(&gcur[t], cnt[t]);
    cur[t] = 0;
    __syncthreads();
#pragma unroll
    for (int j = 0; j < 8; ++j) {
        if (myD[j] >= 0) {
            int b = (int)(((unsigned)myD[j] * KB) / N_NODES);
            int slot = atomicAdd(&cur[b], 1);
            pairs[(size_t)b * BCAP + rbase[b] + slot] = make_int2(myS[j], myD[j]);
        }
    }
}

__global__ __launch_bounds__(256) void bucket_base_kernel(const int* __restrict__ gcur,
                                                          int* __restrict__ bbase) {
    int t = threadIdx.x;
    __shared__ int sc[KB];
    int v = gcur[t];
    sc[t] = v;
    __syncthreads();
    for (int off = 1; off < KB; off <<= 1) {
        int x = sc[t];
        int y = (t >= off) ? sc[t - off] : 0;
        __syncthreads();
        sc[t] = x + y;
        __syncthreads();
    }
    bbase[t] = sc[t] - v;
}

// fillB: one block per bucket; local hist + scan in LDS -> row + col.
__global__ __launch_bounds__(512) void fillB_kernel(const int2* __restrict__ pairs,
                                                    const int* __restrict__ gcur,
                                                    const int* __restrict__ bbase,
                                                    int* __restrict__ row,
                                                    int* __restrict__ col) {
    __shared__ int ssrc[BCAP];      // 32 KB
    __shared__ ushort ld16[BCAP];   // 16 KB
    __shared__ int lcnt[NPB], lex[NPB], lcur[NPB];
    __shared__ int sc[512];
    int b = blockIdx.x;
    int t = threadIdx.x;
    int n0 = (b * N_NODES + KB - 1) / KB;
    int n1 = ((b + 1) * N_NODES + KB - 1) / KB;
    if (n1 > N_NODES) n1 = N_NODES;
    int nn = n1 - n0;
    int cnt = gcur[b];
    if (cnt > BCAP) cnt = BCAP;
    int cbase = bbase[b];
    if (t < NPB) { lcnt[t] = 0; lcur[t] = 0; }
    __syncthreads();
    const int2* bp = pairs + (size_t)b * BCAP;
    for (int i = t; i < cnt; i += 512) {
        int2 pr = bp[i];
        int ld = pr.y - n0;
        atomicAdd(&lcnt[ld], 1);
        ld16[i] = (ushort)ld;
        ssrc[i] = pr.x;
    }
    __syncthreads();
    int val = (t < nn) ? lcnt[t] : 0;
    sc[t] = val;
    __syncthreads();
    for (int off = 1; off < 512; off <<= 1) {
        int x = sc[t];
        int y = (t >= off) ? sc[t - off] : 0;
        __syncthreads();
        sc[t] = x + y;
        __syncthreads();
    }
    if (t < nn) {
        int ex = sc[t] - val;
        lex[t] = ex;
        row[n0 + t] = cbase + ex;
    }
    if (b == 0 && t == 0) row[N_NODES] = N_EDGES;
    __syncthreads();
    for (int i = t; i < cnt; i += 512) {
        int ld = ld16[i];
        int pos = cbase + lex[ld] + atomicAdd(&lcur[ld], 1);
        col[pos] = ssrc[i];
    }
}

// ---------------- converts ----------------

__global__ __launch_bounds__(256) void convert_x_kernel(const float* __restrict__ x,
                                                        ushort* __restrict__ xb) {
    int idx = (blockIdx.x * 256 + threadIdx.x) * 4;
    if (idx >= N_NODES * FEAT) return;
    float4 v = *(const float4*)(x + idx);
    ushort4 o;
    o.x = f2bf(v.x); o.y = f2bf(v.y); o.z = f2bf(v.z); o.w = f2bf(v.w);
    *(ushort4*)(xb + idx) = o;
}

// weights fp32 -> (hi, lo) bf16 planes, zero-padded to 128 rows.
__global__ __launch_bounds__(128) void convert_w_kernel(
    const float* w0, const float* w1, const float* w2, const float* w3,
    const float* w4, const float* w5, const float* w6, const float* w7,
    ushort* __restrict__ wp) {
    int m = blockIdx.y;
    int r = blockIdx.x;
    int c = threadIdx.x;
    const float* src;
    switch (m) {
        case 0: src = w0; break; case 1: src = w1; break;
        case 2: src = w2; break; case 3: src = w3; break;
        case 4: src = w4; break; case 5: src = w5; break;
        case 6: src = w6; break; default: src = w7; break;
    }
    int rows = (m >= 6) ? 40 : 128;
    float val = (r < rows) ? src[r * FEAT + c] : 0.f;
    ushort hi = f2bf(val);
    ushort lo = f2bf(val - bf2f(hi));
    wp[(size_t)m * 32768 + r * FEAT + c] = hi;
    wp[(size_t)m * 32768 + 16384 + r * FEAT + c] = lo;
}

// ---------------- fused layer: aggregate (R8 dense gather) + MFMA combine ----
// Block = 64 nodes, 256 threads (4 waves).
// Phase 1: wave w aggregates nodes v0+w*16 .. +15 sequentially using the
//   4-edge-slot x 16-lane dwordx4 gather; normalized bf16 rows -> LDS
//   (272 B row stride, 16B-aligned chunks).
// Phase 2: standard MFMA combine; self-fragment Ah from global, neighbor
//   fragment Aa from LDS. Different blocks sit in different phases on a CU,
//   so MFMA issue hides under gather memory stalls (m114 co-schedule).

__global__ __launch_bounds__(256) void layer_kernel(
    const ushort* __restrict__ hb, const int* __restrict__ row,
    const int* __restrict__ col, const ushort* __restrict__ wp,
    const float* __restrict__ bias, ushort* __restrict__ outB, int doRelu) {
    __shared__ __align__(16) ushort aggL[64][136];  // 272 B stride, 17.4 KB
    int tid = threadIdx.x;
    int lane = tid & 63;
    int w = tid >> 6;
    int v0 = blockIdx.x * 64;

    // ---- phase 1: gather-aggregate ----
    {
        int g = lane >> 4;             // edge slot 0..3
        int flOff = (lane & 15) * 16;  // byte offset of this lane's 16B chunk
        const char* hp = (const char*)hb;
        for (int n = 0; n < 16; ++n) {
            int ln = w * 16 + n;
            int v = v0 + ln;
            int vc = v < N_NODES ? v : N_NODES - 1;
            int beg = row[vc], end = row[vc + 1];
            int deg = end - beg;
            float a0 = 0.f, a1 = 0.f, a2 = 0.f, a3 = 0.f;
            float a4 = 0.f, a5 = 0.f, a6 = 0.f, a7 = 0.f;
            int endq = beg + (deg & ~3);
            for (int i = beg; i < endq; i += 4) {
                int c = col[i + g];
                uint4 p = *(const uint4*)(hp + (((unsigned)c << 8) | (unsigned)flOff));
                a0 += lo16f(p.x); a1 += hi16f(p.x);
                a2 += lo16f(p.y); a3 += hi16f(p.y);
                a4 += lo16f(p.z); a5 += hi16f(p.z);
                a6 += lo16f(p.w); a7 += hi16f(p.w);
            }
            if (endq < end) {
                int e = endq + g;
                bool ok = e < end;
                int c = col[ok ? e : beg];
                uint4 p = *(const uint4*)(hp + (((unsigned)c << 8) | (unsigned)flOff));
                float m = ok ? 1.f : 0.f;
                a0 += m * lo16f(p.x); a1 += m * hi16f(p.x);
                a2 += m * lo16f(p.y); a3 += m * hi16f(p.y);
                a4 += m * lo16f(p.z); a5 += m * hi16f(p.z);
                a6 += m * lo16f(p.w); a7 += m * hi16f(p.w);
            }
            a0 += __shfl_xor(a0, 16); a1 += __shfl_xor(a1, 16);
            a2 += __shfl_xor(a2, 16); a3 += __shfl_xor(a3, 16);
            a4 += __shfl_xor(a4, 16); a5 += __shfl_xor(a5, 16);
            a6 += __shfl_xor(a6, 16); a7 += __shfl_xor(a7, 16);
            a0 += __shfl_xor(a0, 32); a1 += __shfl_xor(a1, 32);
            a2 += __shfl_xor(a2, 32); a3 += __shfl_xor(a3, 32);
            a4 += __shfl_xor(a4, 32); a5 += __shfl_xor(a5, 32);
            a6 += __shfl_xor(a6, 32); a7 += __shfl_xor(a7, 32);
            if (g == 0) {
                float invd = 1.0f / (float)(deg > 0 ? deg : 1);
                uint4 o;
                o.x = (unsigned)f2bf(a0 * invd) | ((unsigned)f2bf(a1 * invd) << 16);
                o.y = (unsigned)f2bf(a2 * invd) | ((unsigned)f2bf(a3 * invd) << 16);
                o.z = (unsigned)f2bf(a4 * invd) | ((unsigned)f2bf(a5 * invd) << 16);
                o.w = (unsigned)f2bf(a6 * invd) | ((unsigned)f2bf(a7 * invd) << 16);
                *(uint4*)&aggL[ln][(lane & 15) * 8] = o;
            }
        }
    }
    __syncthreads();

    // ---- phase 2: combine ----
    int frow = lane & 15;
    int fk = (lane >> 4) * 8;
    int nb = w * 32;

    const ushort* sHi = wp;
    const ushort* sLo = wp + 16384;
    const ushort* nHi = wp + 32768;
    const ushort* nLo = wp + 49152;

    int mnode[4];
#pragma unroll
    for (int mt = 0; mt < 4; ++mt) {
        int v = v0 + mt * 16 + frow;
        mnode[mt] = v < N_NODES ? v : N_NODES - 1;
    }
    int n0 = nb + frow;
    int n1 = nb + 16 + frow;

    f32x4 acc[4][2];
#pragma unroll
    for (int mt = 0; mt < 4; ++mt)
#pragma unroll
        for (int nt = 0; nt < 2; ++nt) acc[mt][nt] = (f32x4)(0.f);

#pragma unroll
    for (int kt = 0; kt < 4; ++kt) {
        int k = kt * 32 + fk;
        bf16x8 Bs[2][2], Bn[2][2];
        Bs[0][0] = *(const bf16x8*)(sHi + n0 * FEAT + k);
        Bs[0][1] = *(const bf16x8*)(sLo + n0 * FEAT + k);
        Bn[0][0] = *(const bf16x8*)(nHi + n0 * FEAT + k);
        Bn[0][1] = *(const bf16x8*)(nLo + n0 * FEAT + k);
        Bs[1][0] = *(const bf16x8*)(sHi + n1 * FEAT + k);
        Bs[1][1] = *(const bf16x8*)(sLo + n1 * FEAT + k);
        Bn[1][0] = *(const bf16x8*)(nHi + n1 * FEAT + k);
        Bn[1][1] = *(const bf16x8*)(nLo + n1 * FEAT + k);
#pragma unroll
        for (int mt = 0; mt < 4; ++mt) {
            bf16x8 Ah = *(const bf16x8*)(hb + (size_t)mnode[mt] * FEAT + k);
            bf16x8 Aa = *(const bf16x8*)&aggL[mt * 16 + frow][k];
#pragma unroll
            for (int nt = 0; nt < 2; ++nt) {
                f32x4 c = acc[mt][nt];
                c = MFMA(Ah, Bs[nt][0], c);
                c = MFMA(Ah, Bs[nt][1], c);
                c = MFMA(Aa, Bn[nt][0], c);
                c = MFMA(Aa, Bn[nt][1], c);
                acc[mt][nt] = c;
            }
        }
    }

#pragma unroll
    for (int nt = 0; nt < 2; ++nt) {
        int colo = nb + nt * 16 + (lane & 15);
        float b = bias[colo];
#pragma unroll
        for (int mt = 0; mt < 4; ++mt) {
#pragma unroll
            for (int i = 0; i < 4; ++i) {
                int v = v0 + mt * 16 + (lane >> 4) * 4 + i;
                if (v >= N_NODES) continue;
                float r = acc[mt][nt][i] + b;
                if (doRelu) r = fmaxf(r, 0.f);
                outB[(size_t)v * FEAT + colo] = f2bf(r);
            }
        }
    }
}

// ---------------- layer 4: project-then-aggregate ----------------

__global__ __launch_bounds__(256) void proj_kernel(
    const ushort* __restrict__ hb, const ushort* __restrict__ wn,
    ushort* __restrict__ pbuf) {
    int tid = threadIdx.x;
    int lane = tid & 63;
    int w = tid >> 6;
    int v0 = blockIdx.x * 128 + (w >> 1) * 64;
    int nb = (w & 1) * 32;
    int frow = lane & 15;
    int fk = (lane >> 4) * 8;
    const ushort* nHi = wn;
    const ushort* nLo = wn + 16384;

    int mnode[4];
#pragma unroll
    for (int mt = 0; mt < 4; ++mt) {
        int v = v0 + mt * 16 + frow;
        mnode[mt] = v < N_NODES ? v : N_NODES - 1;
    }
    int n0 = nb + frow;
    int n1 = nb + 16 + frow;

    f32x4 acc[4][2];
#pragma unroll
    for (int mt = 0; mt < 4; ++mt)
#pragma unroll
        for (int nt = 0; nt < 2; ++nt) acc[mt][nt] = (f32x4)(0.f);

#pragma unroll
    for (int kt = 0; kt < 4; ++kt) {
        int k = kt * 32 + fk;
        bf16x8 B0h = *(const bf16x8*)(nHi + n0 * FEAT + k);
        bf16x8 B0l = *(const bf16x8*)(nLo + n0 * FEAT + k);
        bf16x8 B1h = *(const bf16x8*)(nHi + n1 * FEAT + k);
        bf16x8 B1l = *(const bf16x8*)(nLo + n1 * FEAT + k);
#pragma unroll
        for (int mt = 0; mt < 4; ++mt) {
            bf16x8 Ah = *(const bf16x8*)(hb + (size_t)mnode[mt] * FEAT + k);
            f32x4 c0 = acc[mt][0];
            c0 = MFMA(Ah, B0h, c0);
            c0 = MFMA(Ah, B0l, c0);
            acc[mt][0] = c0;
            f32x4 c1 = acc[mt][1];
            c1 = MFMA(Ah, B1h, c1);
            c1 = MFMA(Ah, B1l, c1);
            acc[mt][1] = c1;
        }
    }

#pragma unroll
    for (int nt = 0; nt < 2; ++nt) {
        int colo = nb + nt * 16 + (lane & 15);
        if (colo >= 40) continue;
#pragma unroll
        for (int mt = 0; mt < 4; ++mt) {
#pragma unroll
            for (int i = 0; i < 4; ++i) {
                int v = v0 + mt * 16 + (lane >> 4) * 4 + i;
                if (v >= N_NODES) continue;
                pbuf[(size_t)v * 40 + colo] = f2bf(acc[mt][nt][i]);
            }
        }
    }
}

__global__ __launch_bounds__(256) void agg4_kernel(const ushort* __restrict__ pbuf,
                                                   const int* __restrict__ row,
                                                   const int* __restrict__ col,
                                                   float* __restrict__ aggP) {
    int t = blockIdx.x * 256 + threadIdx.x;
    int v = t >> 5;
    int l = t & 31;
    if (v >= N_NODES || l >= 20) return;
    int beg = row[v], end = row[v + 1];
    const unsigned int* base = (const unsigned int*)pbuf;
    float s0 = 0.f, s1 = 0.f;
    int i = beg;
    for (; i + 4 <= end; i += 4) {
        int c0 = col[i], c1 = col[i + 1], c2 = col[i + 2], c3 = col[i + 3];
        unsigned int p0 = base[(size_t)c0 * 20 + l];
        unsigned int p1 = base[(size_t)c1 * 20 + l];
        unsigned int p2 = base[(size_t)c2 * 20 + l];
        unsigned int p3 = base[(size_t)c3 * 20 + l];
        s0 += lo16f(p0); s1 += hi16f(p0);
        s0 += lo16f(p1); s1 += hi16f(p1);
        s0 += lo16f(p2); s1 += hi16f(p2);
        s0 += lo16f(p3); s1 += hi16f(p3);
    }
    for (; i < end; ++i) {
        unsigned int p = base[(size_t)col[i] * 20 + l];
        s0 += lo16f(p); s1 += hi16f(p);
    }
    int deg = end - beg;
    float invd = 1.0f / (float)(deg > 0 ? deg : 1);
    float2 o; o.x = s0 * invd; o.y = s1 * invd;
    *(float2*)(aggP + (size_t)v * 40 + 2 * l) = o;
}

__global__ __launch_bounds__(128) void combine4_kernel(
    const ushort* __restrict__ hb, const ushort* __restrict__ ws,
    const float* __restrict__ aggP, const float* __restrict__ bias,
    float* __restrict__ out) {
    int tid = threadIdx.x;
    int lane = tid & 63;
    int w = tid >> 6;
    int v0 = blockIdx.x * 64;
    int nb = w * 32;
    int frow = lane & 15;
    int fk = (lane >> 4) * 8;
    const ushort* sHi = ws;
    const ushort* sLo = ws + 16384;

    int mnode[4];
#pragma unroll
    for (int mt = 0; mt < 4; ++mt) {
        int v = v0 + mt * 16 + frow;
        mnode[mt] = v < N_NODES ? v : N_NODES - 1;
    }
    int n0 = nb + frow;
    int n1 = nb + 16 + frow;

    f32x4 acc[4][2];
#pragma unroll
    for (int mt = 0; mt < 4; ++mt)
#pragma unroll
        for (int nt = 0; nt < 2; ++nt) acc[mt][nt] = (f32x4)(0.f);

#pragma unroll
    for (int kt = 0; kt < 4; ++kt) {
        int k = kt * 32 + fk;
        bf16x8 B0h = *(const bf16x8*)(sHi + n0 * FEAT + k);
        bf16x8 B0l = *(const bf16x8*)(sLo + n0 * FEAT + k);
        bf16x8 B1h = *(const bf16x8*)(sHi + n1 * FEAT + k);
        bf16x8 B1l = *(const bf16x8*)(sLo + n1 * FEAT + k);
#pragma unroll
        for (int mt = 0; mt < 4; ++mt) {
            bf16x8 Ah = *(const bf16x8*)(hb + (size_t)mnode[mt] * FEAT + k);
            f32x4 c0 = acc[mt][0];
            c0 = MFMA(Ah, B0h, c0);
            c0 = MFMA(Ah, B0l, c0);
            acc[mt][0] = c0;
            f32x4 c1 = acc[mt][1];
            c1 = MFMA(Ah, B1h, c1);
            c1 = MFMA(Ah, B1l, c1);
            acc[mt][1] = c1;
        }
    }

#pragma unroll
    for (int nt = 0; nt < 2; ++nt) {
        int colo = nb + nt * 16 + (lane & 15);
        if (colo >= 40) continue;
        float b = bias[colo];
#pragma unroll
        for (int mt = 0; mt < 4; ++mt) {
#pragma unroll
            for (int i = 0; i < 4; ++i) {
                int v = v0 + mt * 16 + (lane >> 4) * 4 + i;
                if (v >= N_NODES) continue;
                out[(size_t)v * 40 + colo] = acc[mt][nt][i] + b + aggP[(size_t)v * 40 + colo];
            }
        }
    }
}

// ---------------- launch ----------------

static inline size_t align256(size_t x) { return (x + 255) & ~(size_t)255; }

extern "C" void kernel_launch(void* const* d_in, const int* in_sizes, int n_in,
                              void* d_out, int out_size, void* d_ws, size_t ws_size,
                              hipStream_t stream) {
    const float* x = (const float*)d_in[0];
    const int* src = (const int*)d_in[1];
    const int* dst = (const int*)d_in[2];
    const float* ws1 = (const float*)d_in[3];
    const float* wn1 = (const float*)d_in[4];
    const float* b1 = (const float*)d_in[5];
    const float* ws2 = (const float*)d_in[6];
    const float* wn2 = (const float*)d_in[7];
    const float* b2 = (const float*)d_in[8];
    const float* ws3 = (const float*)d_in[9];
    const float* wn3 = (const float*)d_in[10];
    const float* b3 = (const float*)d_in[11];
    const float* ws4 = (const float*)d_in[12];
    const float* wn4 = (const float*)d_in[13];
    const float* b4 = (const float*)d_in[14];
    float* out = (float*)d_out;

    char* base = (char*)d_ws;
    size_t off = 0;
    auto alloc = [&](size_t bytes) -> void* {
        void* p = base + off;
        off = align256(off + bytes);
        return p;
    };
    int* row = (int*)alloc((size_t)(N_NODES + 1) * 4);
    int* gcur = (int*)alloc((size_t)KB * 4);
    int* bbase = (int*)alloc((size_t)KB * 4);
    int* col = (int*)alloc((size_t)N_EDGES * 4);
    int2* pairs = (int2*)alloc((size_t)KB * BCAP * 8);   // 16.8 MB padded buckets
    ushort* wp = (ushort*)alloc((size_t)8 * 32768 * 2);
    ushort* xb = (ushort*)alloc((size_t)N_NODES * FEAT * 2);
    ushort* bufA = (ushort*)alloc((size_t)N_NODES * FEAT * 2);
    ushort* bufB = (ushort*)alloc((size_t)N_NODES * FEAT * 2);
    ushort* pbuf = (ushort*)alloc((size_t)N_NODES * 40 * 2);
    float* aggP = (float*)alloc((size_t)N_NODES * 40 * 4);
    (void)ws_size;

    // converts + CSR build
    convert_x_kernel<<<(N_NODES * FEAT / 4 + 255) / 256, 256, 0, stream>>>(x, xb);
    convert_w_kernel<<<dim3(128, 8), 128, 0, stream>>>(ws1, wn1, ws2, wn2, ws3, wn3,
                                                       ws4, wn4, wp);
    init_gcur_kernel<<<1, KB, 0, stream>>>(gcur);
    fillA_kernel<<<(N_EDGES + TILE - 1) / TILE, 256, 0, stream>>>(src, dst, gcur, pairs);
    bucket_base_kernel<<<1, KB, 0, stream>>>(gcur, bbase);
    fillB_kernel<<<KB, 512, 0, stream>>>(pairs, gcur, bbase, row, col);

    int cgrid = (N_NODES + 63) / 64;  // 1563

    const ushort* wp1 = wp;
    const ushort* wp2 = wp + (size_t)2 * 32768;
    const ushort* wp3 = wp + (size_t)4 * 32768;
    const ushort* wp4 = wp + (size_t)6 * 32768;

    // layers 1-3: fused aggregate+combine
    layer_kernel<<<cgrid, 256, 0, stream>>>(xb, row, col, wp1, b1, bufA, 1);
    layer_kernel<<<cgrid, 256, 0, stream>>>(bufA, row, col, wp2, b2, bufB, 1);
    layer_kernel<<<cgrid, 256, 0, stream>>>(bufB, row, col, wp3, b3, bufA, 1);
    // layer 4: project -> aggregate(40-dim) -> self-combine
    proj_kernel<<<(N_NODES + 127) / 128, 256, 0, stream>>>(bufA, wp4 + 32768, pbuf);
    agg4_kernel<<<((size_t)N_NODES * 32 + 255) / 256, 256, 0, stream>>>(pbuf, row, col, aggP);
    combine4_kernel<<<cgrid, 128, 0, stream>>>(bufA, wp4, aggP, b4, out);
}

// Round 11
// 598.047 us; speedup vs baseline: 1.6425x; 1.2016x over previous
//
#include <hip/hip_runtime.h>

#define N_NODES 100000
#define N_EDGES 1600000
#define FEAT 128
#define KB 256      // coarse buckets for edge partition (node ranges)
#define BCAP 8192   // padded capacity per bucket (mean 6250)
#define TILE 2048   // edges per fillA block
#define NPB 400     // max nodes per bucket (391) padded

typedef short bf16x8 __attribute__((ext_vector_type(8)));
typedef float f32x4 __attribute__((ext_vector_type(4)));

__device__ __forceinline__ ushort f2bf(float x) {
    union { float f; unsigned int u; } v; v.f = x;
    unsigned int u = v.u;
    return (ushort)((u + 0x7fffu + ((u >> 16) & 1u)) >> 16);  // RNE
}
__device__ __forceinline__ float bf2f(ushort h) {
    union { float f; unsigned int u; } v; v.u = ((unsigned int)h) << 16;
    return v.f;
}
__device__ __forceinline__ float lo16f(unsigned int u) {
    union { float f; unsigned int u; } v; v.u = u << 16;
    return v.f;
}
__device__ __forceinline__ float hi16f(unsigned int u) {
    union { float f; unsigned int u; } v; v.u = u & 0xffff0000u;
    return v.f;
}

#define MFMA(a, b, c) __builtin_amdgcn_mfma_f32_16x16x32_bf16((a), (b), (c), 0, 0, 0)

// ---------------- CSR build ----------------

__global__ __launch_bounds__(256) void init_gcur_kernel(int* __restrict__ gcur) {
    gcur[threadIdx.x] = 0;
}

// fillA: per block, LDS count -> reserve run (1 global atomic/bucket) ->
// direct scatter into padded buckets.
__global__ __launch_bounds__(256) void fillA_kernel(const int* __restrict__ src,
                                                    const int* __restrict__ dst,
                                                    int* __restrict__ gcur,
                                                    int2* __restrict__ pairs) {
    __shared__ int cnt[KB];
    __shared__ int cur[KB];
    __shared__ int rbase[KB];
    int t = threadIdx.x;
    int base = blockIdx.x * TILE;
    cnt[t] = 0;
    __syncthreads();
    int myS[8], myD[8];
#pragma unroll
    for (int j = 0; j < 8; ++j) {
        int e = base + j * 256 + t;
        int s = 0, d = -1;
        if (e < N_EDGES) {
            s = src[e]; d = dst[e];
            int b = (int)(((unsigned)d * KB) / N_NODES);
            atomicAdd(&cnt[b], 1);
        }
        myS[j] = s; myD[j] = d;
    }
    __syncthreads();
    rbase[t] = atomicAdd(&gcur[t], cnt[t]);
    cur[t] = 0;
    __syncthreads();
#pragma unroll
    for (int j = 0; j < 8; ++j) {
        if (myD[j] >= 0) {
            int b = (int)(((unsigned)myD[j] * KB) / N_NODES);
            int slot = atomicAdd(&cur[b], 1);
            pairs[(size_t)b * BCAP + rbase[b] + slot] = make_int2(myS[j], myD[j]);
        }
    }
}

__global__ __launch_bounds__(256) void bucket_base_kernel(const int* __restrict__ gcur,
                                                          int* __restrict__ bbase) {
    int t = threadIdx.x;
    __shared__ int sc[KB];
    int v = gcur[t];
    sc[t] = v;
    __syncthreads();
    for (int off = 1; off < KB; off <<= 1) {
        int x = sc[t];
        int y = (t >= off) ? sc[t - off] : 0;
        __syncthreads();
        sc[t] = x + y;
        __syncthreads();
    }
    bbase[t] = sc[t] - v;
}

// fillB: one block per bucket; local hist + scan in LDS -> row + col.
__global__ __launch_bounds__(512) void fillB_kernel(const int2* __restrict__ pairs,
                                                    const int* __restrict__ gcur,
                                                    const int* __restrict__ bbase,
                                                    int* __restrict__ row,
                                                    int* __restrict__ col) {
    __shared__ int ssrc[BCAP];      // 32 KB
    __shared__ ushort ld16[BCAP];   // 16 KB
    __shared__ int lcnt[NPB], lex[NPB], lcur[NPB];
    __shared__ int sc[512];
    int b = blockIdx.x;
    int t = threadIdx.x;
    int n0 = (b * N_NODES + KB - 1) / KB;
    int n1 = ((b + 1) * N_NODES + KB - 1) / KB;
    if (n1 > N_NODES) n1 = N_NODES;
    int nn = n1 - n0;
    int cnt = gcur[b];
    if (cnt > BCAP) cnt = BCAP;
    int cbase = bbase[b];
    if (t < NPB) { lcnt[t] = 0; lcur[t] = 0; }
    __syncthreads();
    const int2* bp = pairs + (size_t)b * BCAP;
    for (int i = t; i < cnt; i += 512) {
        int2 pr = bp[i];
        int ld = pr.y - n0;
        atomicAdd(&lcnt[ld], 1);
        ld16[i] = (ushort)ld;
        ssrc[i] = pr.x;
    }
    __syncthreads();
    int val = (t < nn) ? lcnt[t] : 0;
    sc[t] = val;
    __syncthreads();
    for (int off = 1; off < 512; off <<= 1) {
        int x = sc[t];
        int y = (t >= off) ? sc[t - off] : 0;
        __syncthreads();
        sc[t] = x + y;
        __syncthreads();
    }
    if (t < nn) {
        int ex = sc[t] - val;
        lex[t] = ex;
        row[n0 + t] = cbase + ex;
    }
    if (b == 0 && t == 0) row[N_NODES] = N_EDGES;
    __syncthreads();
    for (int i = t; i < cnt; i += 512) {
        int ld = ld16[i];
        int pos = cbase + lex[ld] + atomicAdd(&lcur[ld], 1);
        col[pos] = ssrc[i];
    }
}

// ---------------- converts ----------------

__global__ __launch_bounds__(256) void convert_x_kernel(const float* __restrict__ x,
                                                        ushort* __restrict__ xb) {
    int idx = (blockIdx.x * 256 + threadIdx.x) * 4;
    if (idx >= N_NODES * FEAT) return;
    float4 v = *(const float4*)(x + idx);
    ushort4 o;
    o.x = f2bf(v.x); o.y = f2bf(v.y); o.z = f2bf(v.z); o.w = f2bf(v.w);
    *(ushort4*)(xb + idx) = o;
}

// weights fp32 -> (hi, lo) bf16 planes, zero-padded to 128 rows.
__global__ __launch_bounds__(128) void convert_w_kernel(
    const float* w0, const float* w1, const float* w2, const float* w3,
    const float* w4, const float* w5, const float* w6, const float* w7,
    ushort* __restrict__ wp) {
    int m = blockIdx.y;
    int r = blockIdx.x;
    int c = threadIdx.x;
    const float* src;
    switch (m) {
        case 0: src = w0; break; case 1: src = w1; break;
        case 2: src = w2; break; case 3: src = w3; break;
        case 4: src = w4; break; case 5: src = w5; break;
        case 6: src = w6; break; default: src = w7; break;
    }
    int rows = (m >= 6) ? 40 : 128;
    float val = (r < rows) ? src[r * FEAT + c] : 0.f;
    ushort hi = f2bf(val);
    ushort lo = f2bf(val - bf2f(hi));
    wp[(size_t)m * 32768 + r * FEAT + c] = hi;
    wp[(size_t)m * 32768 + 16384 + r * FEAT + c] = lo;
}

// ---------------- aggregation: dense, 8-edge unroll ----------------
// One wave per node. lane = g*16 + fl: g = edge slot (0..3), fl = 16B chunk.
// Main loop: 2 col loads then 2 independent dwordx4 feature loads in flight
// (8 edges/iter) to double memory-level parallelism vs the 4-edge version.

__global__ __launch_bounds__(256) void agg_kernel(const ushort* __restrict__ hb,
                                                  const int* __restrict__ row,
                                                  const int* __restrict__ col,
                                                  ushort* __restrict__ aggB) {
    int t = blockIdx.x * 256 + threadIdx.x;
    int v = t >> 6;
    int lane = t & 63;
    if (v >= N_NODES) return;
    int g = lane >> 4;
    int flOff = (lane & 15) * 16;  // byte offset of this lane's 16B chunk
    int beg = row[v], end = row[v + 1];
    int deg = end - beg;
    float a0 = 0.f, a1 = 0.f, a2 = 0.f, a3 = 0.f;
    float a4 = 0.f, a5 = 0.f, a6 = 0.f, a7 = 0.f;
    const char* hp = (const char*)hb;
    int i = beg;
    int end8 = beg + (deg & ~7);
    for (; i < end8; i += 8) {
        int c0 = col[i + g];
        int c1 = col[i + 4 + g];
        uint4 p0 = *(const uint4*)(hp + (((unsigned)c0 << 8) | (unsigned)flOff));
        uint4 p1 = *(const uint4*)(hp + (((unsigned)c1 << 8) | (unsigned)flOff));
        a0 += lo16f(p0.x); a1 += hi16f(p0.x);
        a2 += lo16f(p0.y); a3 += hi16f(p0.y);
        a4 += lo16f(p0.z); a5 += hi16f(p0.z);
        a6 += lo16f(p0.w); a7 += hi16f(p0.w);
        a0 += lo16f(p1.x); a1 += hi16f(p1.x);
        a2 += lo16f(p1.y); a3 += hi16f(p1.y);
        a4 += lo16f(p1.z); a5 += hi16f(p1.z);
        a6 += lo16f(p1.w); a7 += hi16f(p1.w);
    }
    if (i + 4 <= end) {
        int c = col[i + g];
        uint4 p = *(const uint4*)(hp + (((unsigned)c << 8) | (unsigned)flOff));
        a0 += lo16f(p.x); a1 += hi16f(p.x);
        a2 += lo16f(p.y); a3 += hi16f(p.y);
        a4 += lo16f(p.z); a5 += hi16f(p.z);
        a6 += lo16f(p.w); a7 += hi16f(p.w);
        i += 4;
    }
    if (i < end) {
        int e = i + g;
        bool ok = e < end;
        int c = col[ok ? e : beg];
        uint4 p = *(const uint4*)(hp + (((unsigned)c << 8) | (unsigned)flOff));
        float m = ok ? 1.f : 0.f;
        a0 += m * lo16f(p.x); a1 += m * hi16f(p.x);
        a2 += m * lo16f(p.y); a3 += m * hi16f(p.y);
        a4 += m * lo16f(p.z); a5 += m * hi16f(p.z);
        a6 += m * lo16f(p.w); a7 += m * hi16f(p.w);
    }
    // reduce across edge slots (lanes fl, fl+16, fl+32, fl+48)
    a0 += __shfl_xor(a0, 16); a1 += __shfl_xor(a1, 16);
    a2 += __shfl_xor(a2, 16); a3 += __shfl_xor(a3, 16);
    a4 += __shfl_xor(a4, 16); a5 += __shfl_xor(a5, 16);
    a6 += __shfl_xor(a6, 16); a7 += __shfl_xor(a7, 16);
    a0 += __shfl_xor(a0, 32); a1 += __shfl_xor(a1, 32);
    a2 += __shfl_xor(a2, 32); a3 += __shfl_xor(a3, 32);
    a4 += __shfl_xor(a4, 32); a5 += __shfl_xor(a5, 32);
    a6 += __shfl_xor(a6, 32); a7 += __shfl_xor(a7, 32);
    if (g == 0) {
        float invd = 1.0f / (float)(deg > 0 ? deg : 1);
        uint4 o;
        o.x = (unsigned)f2bf(a0 * invd) | ((unsigned)f2bf(a1 * invd) << 16);
        o.y = (unsigned)f2bf(a2 * invd) | ((unsigned)f2bf(a3 * invd) << 16);
        o.z = (unsigned)f2bf(a4 * invd) | ((unsigned)f2bf(a5 * invd) << 16);
        o.w = (unsigned)f2bf(a6 * invd) | ((unsigned)f2bf(a7 * invd) << 16);
        *(uint4*)((char*)aggB + (((size_t)v << 8) | (unsigned)flOff)) = o;
    }
}

// ---------------- combine (layers 1-3): LDS-free bf16 MFMA ----------------

__global__ __launch_bounds__(256) void combine_kernel(
    const ushort* __restrict__ hb, const ushort* __restrict__ aggB,
    const ushort* __restrict__ wp,   // [sHi|sLo|nHi|nLo] planes
    const float* __restrict__ bias,
    ushort* __restrict__ outB, int doRelu) {
    int tid = threadIdx.x;
    int lane = tid & 63;
    int w = tid >> 6;
    int v0 = blockIdx.x * 64;
    int frow = lane & 15;
    int fk = (lane >> 4) * 8;
    int nb = w * 32;

    const ushort* sHi = wp;
    const ushort* sLo = wp + 16384;
    const ushort* nHi = wp + 32768;
    const ushort* nLo = wp + 49152;

    int mnode[4];
#pragma unroll
    for (int mt = 0; mt < 4; ++mt) {
        int v = v0 + mt * 16 + frow;
        mnode[mt] = v < N_NODES ? v : N_NODES - 1;
    }
    int n0 = nb + frow;
    int n1 = nb + 16 + frow;

    f32x4 acc[4][2];
#pragma unroll
    for (int mt = 0; mt < 4; ++mt)
#pragma unroll
        for (int nt = 0; nt < 2; ++nt) acc[mt][nt] = (f32x4)(0.f);

#pragma unroll
    for (int kt = 0; kt < 4; ++kt) {
        int k = kt * 32 + fk;
        bf16x8 Bs[2][2], Bn[2][2];
        Bs[0][0] = *(const bf16x8*)(sHi + n0 * FEAT + k);
        Bs[0][1] = *(const bf16x8*)(sLo + n0 * FEAT + k);
        Bn[0][0] = *(const bf16x8*)(nHi + n0 * FEAT + k);
        Bn[0][1] = *(const bf16x8*)(nLo + n0 * FEAT + k);
        Bs[1][0] = *(const bf16x8*)(sHi + n1 * FEAT + k);
        Bs[1][1] = *(const bf16x8*)(sLo + n1 * FEAT + k);
        Bn[1][0] = *(const bf16x8*)(nHi + n1 * FEAT + k);
        Bn[1][1] = *(const bf16x8*)(nLo + n1 * FEAT + k);
#pragma unroll
        for (int mt = 0; mt < 4; ++mt) {
            bf16x8 Ah = *(const bf16x8*)(hb + (size_t)mnode[mt] * FEAT + k);
            bf16x8 Aa = *(const bf16x8*)(aggB + (size_t)mnode[mt] * FEAT + k);
#pragma unroll
            for (int nt = 0; nt < 2; ++nt) {
                f32x4 c = acc[mt][nt];
                c = MFMA(Ah, Bs[nt][0], c);
                c = MFMA(Ah, Bs[nt][1], c);
                c = MFMA(Aa, Bn[nt][0], c);
                c = MFMA(Aa, Bn[nt][1], c);
                acc[mt][nt] = c;
            }
        }
    }

#pragma unroll
    for (int nt = 0; nt < 2; ++nt) {
        int colo = nb + nt * 16 + (lane & 15);
        float b = bias[colo];
#pragma unroll
        for (int mt = 0; mt < 4; ++mt) {
#pragma unroll
            for (int i = 0; i < 4; ++i) {
                int v = v0 + mt * 16 + (lane >> 4) * 4 + i;
                if (v >= N_NODES) continue;
                float r = acc[mt][nt][i] + b;
                if (doRelu) r = fmaxf(r, 0.f);
                outB[(size_t)v * FEAT + colo] = f2bf(r);
            }
        }
    }
}

// ---------------- layer 4: project-then-aggregate ----------------

__global__ __launch_bounds__(256) void proj_kernel(
    const ushort* __restrict__ hb, const ushort* __restrict__ wn,
    ushort* __restrict__ pbuf) {
    int tid = threadIdx.x;
    int lane = tid & 63;
    int w = tid >> 6;
    int v0 = blockIdx.x * 128 + (w >> 1) * 64;
    int nb = (w & 1) * 32;
    int frow = lane & 15;
    int fk = (lane >> 4) * 8;
    const ushort* nHi = wn;
    const ushort* nLo = wn + 16384;

    int mnode[4];
#pragma unroll
    for (int mt = 0; mt < 4; ++mt) {
        int v = v0 + mt * 16 + frow;
        mnode[mt] = v < N_NODES ? v : N_NODES - 1;
    }
    int n0 = nb + frow;
    int n1 = nb + 16 + frow;

    f32x4 acc[4][2];
#pragma unroll
    for (int mt = 0; mt < 4; ++mt)
#pragma unroll
        for (int nt = 0; nt < 2; ++nt) acc[mt][nt] = (f32x4)(0.f);

#pragma unroll
    for (int kt = 0; kt < 4; ++kt) {
        int k = kt * 32 + fk;
        bf16x8 B0h = *(const bf16x8*)(nHi + n0 * FEAT + k);
        bf16x8 B0l = *(const bf16x8*)(nLo + n0 * FEAT + k);
        bf16x8 B1h = *(const bf16x8*)(nHi + n1 * FEAT + k);
        bf16x8 B1l = *(const bf16x8*)(nLo + n1 * FEAT + k);
#pragma unroll
        for (int mt = 0; mt < 4; ++mt) {
            bf16x8 Ah = *(const bf16x8*)(hb + (size_t)mnode[mt] * FEAT + k);
            f32x4 c0 = acc[mt][0];
            c0 = MFMA(Ah, B0h, c0);
            c0 = MFMA(Ah, B0l, c0);
            acc[mt][0] = c0;
            f32x4 c1 = acc[mt][1];
            c1 = MFMA(Ah, B1h, c1);
            c1 = MFMA(Ah, B1l, c1);
            acc[mt][1] = c1;
        }
    }

#pragma unroll
    for (int nt = 0; nt < 2; ++nt) {
        int colo = nb + nt * 16 + (lane & 15);
        if (colo >= 40) continue;
#pragma unroll
        for (int mt = 0; mt < 4; ++mt) {
#pragma unroll
            for (int i = 0; i < 4; ++i) {
                int v = v0 + mt * 16 + (lane >> 4) * 4 + i;
                if (v >= N_NODES) continue;
                pbuf[(size_t)v * 40 + colo] = f2bf(acc[mt][nt][i]);
            }
        }
    }
}

__global__ __launch_bounds__(256) void agg4_kernel(const ushort* __restrict__ pbuf,
                                                   const int* __restrict__ row,
                                                   const int* __restrict__ col,
                                                   float* __restrict__ aggP) {
    int t = blockIdx.x * 256 + threadIdx.x;
    int v = t >> 5;
    int l = t & 31;
    if (v >= N_NODES || l >= 20) return;
    int beg = row[v], end = row[v + 1];
    const unsigned int* base = (const unsigned int*)pbuf;
    float s0 = 0.f, s1 = 0.f;
    int i = beg;
    for (; i + 4 <= end; i += 4) {
        int c0 = col[i], c1 = col[i + 1], c2 = col[i + 2], c3 = col[i + 3];
        unsigned int p0 = base[(size_t)c0 * 20 + l];
        unsigned int p1 = base[(size_t)c1 * 20 + l];
        unsigned int p2 = base[(size_t)c2 * 20 + l];
        unsigned int p3 = base[(size_t)c3 * 20 + l];
        s0 += lo16f(p0); s1 += hi16f(p0);
        s0 += lo16f(p1); s1 += hi16f(p1);
        s0 += lo16f(p2); s1 += hi16f(p2);
        s0 += lo16f(p3); s1 += hi16f(p3);
    }
    for (; i < end; ++i) {
        unsigned int p = base[(size_t)col[i] * 20 + l];
        s0 += lo16f(p); s1 += hi16f(p);
    }
    int deg = end - beg;
    float invd = 1.0f / (float)(deg > 0 ? deg : 1);
    float2 o; o.x = s0 * invd; o.y = s1 * invd;
    *(float2*)(aggP + (size_t)v * 40 + 2 * l) = o;
}

__global__ __launch_bounds__(128) void combine4_kernel(
    const ushort* __restrict__ hb, const ushort* __restrict__ ws,
    const float* __restrict__ aggP, const float* __restrict__ bias,
    float* __restrict__ out) {
    int tid = threadIdx.x;
    int lane = tid & 63;
    int w = tid >> 6;
    int v0 = blockIdx.x * 64;
    int nb = w * 32;
    int frow = lane & 15;
    int fk = (lane >> 4) * 8;
    const ushort* sHi = ws;
    const ushort* sLo = ws + 16384;

    int mnode[4];
#pragma unroll
    for (int mt = 0; mt < 4; ++mt) {
        int v = v0 + mt * 16 + frow;
        mnode[mt] = v < N_NODES ? v : N_NODES - 1;
    }
    int n0 = nb + frow;
    int n1 = nb + 16 + frow;

    f32x4 acc[4][2];
#pragma unroll
    for (int mt = 0; mt < 4; ++mt)
#pragma unroll
        for (int nt = 0; nt < 2; ++nt) acc[mt][nt] = (f32x4)(0.f);

#pragma unroll
    for (int kt = 0; kt < 4; ++kt) {
        int k = kt * 32 + fk;
        bf16x8 B0h = *(const bf16x8*)(sHi + n0 * FEAT + k);
        bf16x8 B0l = *(const bf16x8*)(sLo + n0 * FEAT + k);
        bf16x8 B1h = *(const bf16x8*)(sHi + n1 * FEAT + k);
        bf16x8 B1l = *(const bf16x8*)(sLo + n1 * FEAT + k);
#pragma unroll
        for (int mt = 0; mt < 4; ++mt) {
            bf16x8 Ah = *(const bf16x8*)(hb + (size_t)mnode[mt] * FEAT + k);
            f32x4 c0 = acc[mt][0];
            c0 = MFMA(Ah, B0h, c0);
            c0 = MFMA(Ah, B0l, c0);
            acc[mt][0] = c0;
            f32x4 c1 = acc[mt][1];
            c1 = MFMA(Ah, B1h, c1);
            c1 = MFMA(Ah, B1l, c1);
            acc[mt][1] = c1;
        }
    }

#pragma unroll
    for (int nt = 0; nt < 2; ++nt) {
        int colo = nb + nt * 16 + (lane & 15);
        if (colo >= 40) continue;
        float b = bias[colo];
#pragma unroll
        for (int mt = 0; mt < 4; ++mt) {
#pragma unroll
            for (int i = 0; i < 4; ++i) {
                int v = v0 + mt * 16 + (lane >> 4) * 4 + i;
                if (v >= N_NODES) continue;
                out[(size_t)v * 40 + colo] = acc[mt][nt][i] + b + aggP[(size_t)v * 40 + colo];
            }
        }
    }
}

// ---------------- launch ----------------

static inline size_t align256(size_t x) { return (x + 255) & ~(size_t)255; }

extern "C" void kernel_launch(void* const* d_in, const int* in_sizes, int n_in,
                              void* d_out, int out_size, void* d_ws, size_t ws_size,
                              hipStream_t stream) {
    const float* x = (const float*)d_in[0];
    const int* src = (const int*)d_in[1];
    const int* dst = (const int*)d_in[2];
    const float* ws1 = (const float*)d_in[3];
    const float* wn1 = (const float*)d_in[4];
    const float* b1 = (const float*)d_in[5];
    const float* ws2 = (const float*)d_in[6];
    const float* wn2 = (const float*)d_in[7];
    const float* b2 = (const float*)d_in[8];
    const float* ws3 = (const float*)d_in[9];
    const float* wn3 = (const float*)d_in[10];
    const float* b3 = (const float*)d_in[11];
    const float* ws4 = (const float*)d_in[12];
    const float* wn4 = (const float*)d_in[13];
    const float* b4 = (const float*)d_in[14];
    float* out = (float*)d_out;

    char* base = (char*)d_ws;
    size_t off = 0;
    auto alloc = [&](size_t bytes) -> void* {
        void* p = base + off;
        off = align256(off + bytes);
        return p;
    };
    int* row = (int*)alloc((size_t)(N_NODES + 1) * 4);
    int* gcur = (int*)alloc((size_t)KB * 4);
    int* bbase = (int*)alloc((size_t)KB * 4);
    int* col = (int*)alloc((size_t)N_EDGES * 4);
    int2* pairs = (int2*)alloc((size_t)KB * BCAP * 8);   // 16.8 MB padded buckets
    ushort* wp = (ushort*)alloc((size_t)8 * 32768 * 2);
    ushort* xb = (ushort*)alloc((size_t)N_NODES * FEAT * 2);
    ushort* bufA = (ushort*)alloc((size_t)N_NODES * FEAT * 2);
    ushort* bufB = (ushort*)alloc((size_t)N_NODES * FEAT * 2);
    ushort* aggB = (ushort*)alloc((size_t)N_NODES * FEAT * 2);
    ushort* pbuf = (ushort*)alloc((size_t)N_NODES * 40 * 2);
    float* aggP = (float*)alloc((size_t)N_NODES * 40 * 4);
    (void)ws_size;

    // converts + CSR build
    convert_x_kernel<<<(N_NODES * FEAT / 4 + 255) / 256, 256, 0, stream>>>(x, xb);
    convert_w_kernel<<<dim3(128, 8), 128, 0, stream>>>(ws1, wn1, ws2, wn2, ws3, wn3,
                                                       ws4, wn4, wp);
    init_gcur_kernel<<<1, KB, 0, stream>>>(gcur);
    fillA_kernel<<<(N_EDGES + TILE - 1) / TILE, 256, 0, stream>>>(src, dst, gcur, pairs);
    bucket_base_kernel<<<1, KB, 0, stream>>>(gcur, bbase);
    fillB_kernel<<<KB, 512, 0, stream>>>(pairs, gcur, bbase, row, col);

    int cgrid = (N_NODES + 63) / 64;                    // 1563
    int aggGrid = ((size_t)N_NODES * 64 + 255) / 256;   // 25000

    const ushort* wp1 = wp;
    const ushort* wp2 = wp + (size_t)2 * 32768;
    const ushort* wp3 = wp + (size_t)4 * 32768;
    const ushort* wp4 = wp + (size_t)6 * 32768;

    agg_kernel<<<aggGrid, 256, 0, stream>>>(xb, row, col, aggB);
    combine_kernel<<<cgrid, 256, 0, stream>>>(xb, aggB, wp1, b1, bufA, 1);
    agg_kernel<<<aggGrid, 256, 0, stream>>>(bufA, row, col, aggB);
    combine_kernel<<<cgrid, 256, 0, stream>>>(bufA, aggB, wp2, b2, bufB, 1);
    agg_kernel<<<aggGrid, 256, 0, stream>>>(bufB, row, col, aggB);
    combine_kernel<<<cgrid, 256, 0, stream>>>(bufB, aggB, wp3, b3, bufA, 1);
    // layer 4: project -> aggregate(40-dim) -> self-combine
    proj_kernel<<<(N_NODES + 127) / 128, 256, 0, stream>>>(bufA, wp4 + 32768, pbuf);
    agg4_kernel<<<((size_t)N_NODES * 32 + 255) / 256, 256, 0, stream>>>(pbuf, row, col, aggP);
    combine4_kernel<<<cgrid, 128, 0, stream>>>(bufA, wp4, aggP, b4, out);
}